// Round 8
// baseline (304.079 us; speedup 1.0000x reference)
//
#include <hip/hip_runtime.h>

#define HEADS 24
#define KVH   6
#define HD    64
#define BB    2
#define SS    2048
#define DD    1536
#define KVD   384      // KVH*HD
#define QKD   1920     // DD + KVD (Q|K only; V lives in VT)
#define MM    4096     // BB*SS

typedef unsigned short ushort_t;
typedef __attribute__((ext_vector_type(8))) short short8;
typedef __attribute__((ext_vector_type(4))) short short4v;
typedef __attribute__((ext_vector_type(4))) float f32x4;

__device__ __forceinline__ ushort_t f2bf(float f) {
    union { float f; unsigned u; } v; v.f = f;
    return (ushort_t)((v.u + 0x8000u) >> 16);
}
__device__ __forceinline__ unsigned pk2(float a, float b) {
    union { float f; unsigned u; } x, y; x.f = a; y.f = b;
    return ((x.u + 0x8000u) >> 16) | (((y.u + 0x8000u) >> 16) << 16);
}
// truncation pack (P values: common-mode cancels in softmax)
__device__ __forceinline__ unsigned pk2t(float a, float b) {
    union { float f; unsigned u; } x, y; x.f = a; y.f = b;
    return (x.u >> 16) | (y.u & 0xFFFF0000u);
}
// Schraudolph fast 2^s (±3.5% rel; cancels in p/Σp)
__device__ __forceinline__ float fexp2(float s) {
    float t = fmaf(s, 8388608.0f, 1065055420.0f);   // (127 - 0.0355) * 2^23
    union { int i; float f; } v; v.i = (int)t;
    return v.f;
}
// 16B frag read from an 8B-aligned LDS row: two b64 halves.
__device__ __forceinline__ short8 lds_frag8(const ushort_t* p) {
    short4v lo = *(const short4v*)p;
    short4v hi = *(const short4v*)(p + 4);
    return __builtin_shufflevector(lo, hi, 0, 1, 2, 3, 4, 5, 6, 7);
}
// async global->LDS, 16B per lane; lds ptr must be wave-uniform base.
__device__ __forceinline__ void glds16(const void* g, void* l) {
    __builtin_amdgcn_global_load_lds(
        (const __attribute__((address_space(1))) void*)g,
        (__attribute__((address_space(3))) void*)l, 16, 0, 0);
}

// ---------------------------------------------------------------------------
// K0: fused preprocessing — cvt X + 4x weight transpose-convert.
// ---------------------------------------------------------------------------
__device__ __forceinline__ void tconv_body(const float* __restrict__ in,
                                           ushort_t* __restrict__ out,
                                           int R, int C, int cb, int rb)
{
    __shared__ ushort_t tile[32][33];
    const int tx = threadIdx.x & 31, ty = threadIdx.x >> 5;
    const int c0 = cb * 32, r0 = rb * 32;
#pragma unroll
    for (int i = 0; i < 4; ++i)
        tile[ty + i * 8][tx] = f2bf(in[(size_t)(r0 + ty + i * 8) * C + c0 + tx]);
    __syncthreads();
#pragma unroll
    for (int i = 0; i < 4; ++i)
        out[(size_t)(c0 + ty + i * 8) * R + r0 + tx] = tile[tx][ty + i * 8];
}

#define NCVT (MM * DD / 4 / 256)     // 6144
__global__ __launch_bounds__(256) void k_prep(const float* __restrict__ HS,
                                              const float* __restrict__ Wq,
                                              const float* __restrict__ Wk,
                                              const float* __restrict__ Wv,
                                              const float* __restrict__ Wo,
                                              ushort_t* __restrict__ Xbf,
                                              ushort_t* __restrict__ Wqt,
                                              ushort_t* __restrict__ Wkt,
                                              ushort_t* __restrict__ Wvt,
                                              ushort_t* __restrict__ Wot)
{
    int bid = blockIdx.x;
    if (bid < NCVT) {
        int i = bid * 256 + threadIdx.x;
        float4 v = ((const float4*)HS)[i];
        uint2 o = { pk2(v.x, v.y), pk2(v.z, v.w) };
        ((uint2*)Xbf)[i] = o;
        return;
    }
    bid -= NCVT;
    if (bid < 2304) { tconv_body(Wq, Wqt, DD, DD,  bid % 48, bid / 48); return; }
    bid -= 2304;
    if (bid < 576)  { tconv_body(Wk, Wkt, DD, KVD, bid % 12, bid / 12); return; }
    bid -= 576;
    if (bid < 576)  { tconv_body(Wv, Wvt, DD, KVD, bid % 12, bid / 12); return; }
    bid -= 576;
    tconv_body(Wo, Wot, DD, DD, bid % 48, bid / 48);
}

// ---------------------------------------------------------------------------
// K1: fused projection dispatch (R4 structure).
//   bid <  480 : Q|K projection, 128x128 tiles + RoPE + Q-scale
//   bid >= 480 : V^T GEMM -> VT, k-PERMUTED slot map
//                s = 32*kc + 8*quad + 2*r + j4 <-> tok = 32*kc+16*j4+4*quad+r
// ---------------------------------------------------------------------------
__global__ __launch_bounds__(256) void k_proj(const ushort_t* __restrict__ Xbf,
                                              const ushort_t* __restrict__ Wqt,
                                              const ushort_t* __restrict__ Wkt,
                                              const ushort_t* __restrict__ Wvt,
                                              const float* __restrict__ cosb,
                                              const float* __restrict__ sinb,
                                              ushort_t* __restrict__ QKVb,
                                              ushort_t* __restrict__ VT)
{
    __shared__ ushort_t As[128][32];
    __shared__ ushort_t Bs[128][32];
    const int t = threadIdx.x, lane = t & 63, wave = t >> 6;
    const int n16 = lane & 15, quad = lane >> 4;
    const int wr = wave >> 1, wc = wave & 1;
    const int srow = lane >> 2;
    const int scol = (lane & 3) * 8;

    if (blockIdx.x < 480) {
        // ---------------- Q|K projection ----------------
        const int nt = blockIdx.x % 15;
        const int n0 = nt * 128;
        const int m0 = (blockIdx.x / 15) * 128;
        const ushort_t* Bt; int nl, isq;
        if (nt < 12) { Bt = Wqt; nl = n0;      isq = 1; }
        else         { Bt = Wkt; nl = n0 - DD; isq = 0; }

        const size_t aoff0 = (size_t)(m0 + wave * 16 + srow) * DD + scol;
        const size_t aoff1 = (size_t)(m0 + (wave + 4) * 16 + srow) * DD + scol;
        const size_t boff0 = (size_t)(nl + wave * 16 + srow) * DD + scol;
        const size_t boff1 = (size_t)(nl + (wave + 4) * 16 + srow) * DD + scol;
        ushort_t* lA0 = &As[wave * 16][0];
        ushort_t* lA1 = &As[(wave + 4) * 16][0];
        ushort_t* lB0 = &Bs[wave * 16][0];
        ushort_t* lB1 = &Bs[(wave + 4) * 16][0];

        f32x4 acc[4][4] = {};
        for (int k0 = 0; k0 < DD; k0 += 32) {
            __syncthreads();
            glds16(Xbf + aoff0 + k0, lA0);
            glds16(Xbf + aoff1 + k0, lA1);
            glds16(Bt  + boff0 + k0, lB0);
            glds16(Bt  + boff1 + k0, lB1);
            __syncthreads();
            short8 af[4], bf8[4];
#pragma unroll
            for (int i = 0; i < 4; ++i) af[i]  = *(const short8*)&As[wr * 64 + i * 16 + n16][quad * 8];
#pragma unroll
            for (int j = 0; j < 4; ++j) bf8[j] = *(const short8*)&Bs[wc * 64 + j * 16 + n16][quad * 8];
#pragma unroll
            for (int i = 0; i < 4; ++i)
#pragma unroll
                for (int j = 0; j < 4; ++j)
                    acc[i][j] = __builtin_amdgcn_mfma_f32_16x16x32_bf16(af[i], bf8[j], acc[i][j], 0, 0, 0);
        }

        const float QSC = 0.18033688011112042f;   // 0.125 * log2(e)
#pragma unroll
        for (int i = 0; i < 4; ++i) {
#pragma unroll
            for (int r = 0; r < 4; ++r) {
                const int row = m0 + wr * 64 + i * 16 + quad * 4 + r;
                ushort_t* outp = QKVb + (size_t)row * QKD + n0 + wc * 64 + n16;
                float v0 = acc[i][0][r], v1 = acc[i][1][r];
                float v2 = acc[i][2][r], v3 = acc[i][3][r];
                {   // partial RoPE on head dims 0..31 (Q and K)
                    const int s = row & (SS - 1);
                    float c0 = cosb[s * 32 + n16],      s0 = sinb[s * 32 + n16];
                    float c1 = cosb[s * 32 + 16 + n16], s1 = sinb[s * 32 + 16 + n16];
                    float nr = v0 * c0 - v1 * s0;
                    float ni = v1 * c1 + v0 * s1;
                    v0 = nr; v1 = ni;
                }
                if (isq) { v0 *= QSC; v1 *= QSC; v2 *= QSC; v3 *= QSC; }
                outp[0]  = f2bf(v0);
                outp[16] = f2bf(v1);
                outp[32] = f2bf(v2);
                outp[48] = f2bf(v3);
            }
        }
    } else {
        // ---------------- V^T GEMM (k-permuted epilogue) ----------------
        const int vb = blockIdx.x - 480;
        const int n0 = (vb & 31) * 128;    // tokens
        const int m0 = (vb >> 5) * 64;     // channels c

        const size_t aoff  = (size_t)(m0 + wave * 16 + srow) * DD + scol;
        const size_t boff0 = (size_t)(n0 + wave * 32 + srow) * DD + scol;
        const size_t boff1 = boff0 + (size_t)16 * DD;
        ushort_t* lA  = &As[wave * 16][0];
        ushort_t* lB0 = &Bs[wave * 32][0];
        ushort_t* lB1 = &Bs[wave * 32 + 16][0];

        f32x4 acc[2][4] = {};
        for (int k0 = 0; k0 < DD; k0 += 32) {
            __syncthreads();
            glds16(Wvt + aoff  + k0, lA);
            glds16(Xbf + boff0 + k0, lB0);
            glds16(Xbf + boff1 + k0, lB1);
            __syncthreads();
            short8 af[2], bf8[4];
#pragma unroll
            for (int i = 0; i < 2; ++i) af[i]  = *(const short8*)&As[wr * 32 + i * 16 + n16][quad * 8];
#pragma unroll
            for (int j = 0; j < 4; ++j) bf8[j] = *(const short8*)&Bs[wc * 64 + j * 16 + n16][quad * 8];
#pragma unroll
            for (int i = 0; i < 2; ++i)
#pragma unroll
                for (int j = 0; j < 4; ++j)
                    acc[i][j] = __builtin_amdgcn_mfma_f32_16x16x32_bf16(af[i], bf8[j], acc[i][j], 0, 0, 0);
        }

        const int b = n0 >> 11;            // token tile never straddles batch
        const int s0 = 8 * (n16 >> 2) + 2 * (n16 & 3);
#pragma unroll
        for (int i = 0; i < 2; ++i)
#pragma unroll
            for (int r = 0; r < 4; ++r) {
                const int c = m0 + wr * 32 + i * 16 + quad * 4 + r;
                ushort_t* op = VT + ((size_t)b * KVD + c) * SS +
                               (n0 & (SS - 1)) + wc * 64 + s0;
                *(unsigned*)op        = pk2(acc[i][0][r], acc[i][1][r]);
                *(unsigned*)(op + 32) = pk2(acc[i][2][r], acc[i][3][r]);
            }
    }
}

// ---------------------------------------------------------------------------
// K3: MFMA bf16 flash attention — swapped QK^T, in-register P, fast-exp2.
// ROUND 8 change: 8 waves = 4 q-groups (32q, m=2) x 2 K-PARITIES.
//   R7's LDS wall: 8 waves all read every tile -> 8192 b64 reads/block
//   (~69us issue demand = the measured 76.6us).  Parity-split: each tile is
//   read by only the 4 waves of its parity -> 4096 reads/block (~38us
//   demand), MFMA/VALU totals unchanged, TLP stays >= 16 waves/CU.
//   Buffers are per-parity (pair double-buffer, 2 barriers/pair = same
//   1-per-tile count), prefetch-1 reg staging kept.  Exact cross-parity
//   combine at the end (no max-tracking => fully associative):
//   l = l0+l1, O = (A0+A1)/l, via one-time LDS scratch pass.
// ---------------------------------------------------------------------------
__global__ __launch_bounds__(512, 4) void k_attn(const ushort_t* __restrict__ QKVb,
                                                 const ushort_t* __restrict__ VT,
                                                 ushort_t* __restrict__ AOb)
{
    // one contiguous block: [0]=K, [1]=V; inner index = parity buffer.
    __shared__ __align__(16) ushort_t SMEM[2][2][64][76];

    const int t    = threadIdx.x;
    const int wave = t >> 6;          // 0..7
    const int qg   = wave & 3;        // q-group (32q each)
    const int par  = wave >> 2;       // k-parity this wave computes
    const int quad = (t >> 4) & 3;
    const int n16  = t & 15;
    const int lane = t & 63;
    const int q0   = blockIdx.x * 128;
    const int h    = blockIdx.y;
    const int b    = blockIdx.z;
    const int kh   = h >> 2;

    // staging role: thread stages tile-parity ps (independent of compute par)
    const int ps = t >> 8;            // 0 or 1
    const int tt = t & 255;
    const int sr = tt >> 2;           // 0..63 staging row
    const int sc = (tt & 3) * 8;      // K staging col
    const int vc = (tt & 3) * 16;     // V staging col

    // loop-invariant Q frags (pre-scaled by 0.125*log2e)
    short8 qf[2][2];
#pragma unroll
    for (int m = 0; m < 2; ++m)
#pragma unroll
        for (int kc = 0; kc < 2; ++kc)
            qf[m][kc] = *(const short8*)(QKVb +
                (size_t)(b * SS + q0 + qg * 32 + m * 16 + n16) * QKD +
                h * HD + kc * 32 + quad * 8);

    float l_p[2] = {};                // per-lane partial row sums (q = n16)
    f32x4 acc_o[2][4] = {};           // C[d][q]: row d = quad*4+r, col q = n16

    const ushort_t* Kbase = QKVb + (size_t)(b * SS) * QKD + DD + kh * HD;
    const ushort_t* Vbase = VT + ((size_t)b * KVD + kh * 64) * SS;

    uint4 kv0, kv1, vv0, vv1;         // prefetch regs: this thread's tile of a pair

#define LOAD_PAIR(I) do {                                                   \
        const int k0s = ((I) * 2 + ps) * 64;                                \
        const ushort_t* Kg = Kbase + (size_t)(k0s + sr) * QKD + sc;         \
        kv0 = *(const uint4*)(Kg);                                          \
        kv1 = *(const uint4*)(Kg + 32);                                     \
        const ushort_t* Vg = Vbase + (size_t)sr * SS + k0s + vc;            \
        vv0 = *(const uint4*)(Vg);                                          \
        vv1 = *(const uint4*)(Vg + 8);                                      \
    } while (0)

#define WRITE_PAIR() do {                                                   \
        *(uint2*)&SMEM[0][ps][sr][sc]      = make_uint2(kv0.x, kv0.y);      \
        *(uint2*)&SMEM[0][ps][sr][sc + 4]  = make_uint2(kv0.z, kv0.w);      \
        *(uint2*)&SMEM[0][ps][sr][sc + 32] = make_uint2(kv1.x, kv1.y);      \
        *(uint2*)&SMEM[0][ps][sr][sc + 36] = make_uint2(kv1.z, kv1.w);      \
        *(uint2*)&SMEM[1][ps][sr][vc]      = make_uint2(vv0.x, vv0.y);      \
        *(uint2*)&SMEM[1][ps][sr][vc + 4]  = make_uint2(vv0.z, vv0.w);      \
        *(uint2*)&SMEM[1][ps][sr][vc + 8]  = make_uint2(vv1.x, vv1.y);      \
        *(uint2*)&SMEM[1][ps][sr][vc + 12] = make_uint2(vv1.z, vv1.w);      \
    } while (0)

    // ---- prologue: pair 0 -> bufs; pair 1 -> regs; barrier ----
    LOAD_PAIR(0);
    WRITE_PAIR();
    LOAD_PAIR(1);
    __syncthreads();

    const int NP = SS / 128;          // 16 pairs of tiles
    for (int i = 0; i < NP; ++i) {
        const ushort_t (*Kc)[76] = SMEM[0][par];
        const ushort_t (*Vc)[76] = SMEM[1][par];

        // ---- swapped QK^T on this wave's tile of the pair ----
        f32x4 sT[2][4] = {};
#pragma unroll
        for (int kc = 0; kc < 2; ++kc) {
            short8 bf[4];
#pragma unroll
            for (int jj = 0; jj < 4; ++jj)
                bf[jj] = lds_frag8(&Kc[jj * 16 + n16][kc * 32 + quad * 8]);
#pragma unroll
            for (int m = 0; m < 2; ++m)
#pragma unroll
                for (int jj = 0; jj < 4; ++jj)
                    sT[m][jj] = __builtin_amdgcn_mfma_f32_16x16x32_bf16(
                        bf[jj], qf[m][kc], sT[m][jj], 0, 0, 0);
        }

        // ---- softmax in-register -> PV B-frag words ----
        union PB { unsigned w[4]; short8 v; };
        PB pb[2][2];
#pragma unroll
        for (int m = 0; m < 2; ++m) {
#pragma unroll
            for (int w = 0; w < 4; ++w) {
                float p0 = fexp2(sT[m][0][w]);
                float p1 = fexp2(sT[m][1][w]);
                float p2 = fexp2(sT[m][2][w]);
                float p3 = fexp2(sT[m][3][w]);
                pb[m][0].w[w] = pk2t(p0, p1);
                pb[m][1].w[w] = pk2t(p2, p3);
                l_p[m] += (p0 + p1) + (p2 + p3);
            }
        }

        // ---- PV ----
#pragma unroll
        for (int kc = 0; kc < 2; ++kc) {
            short8 vb[4];
#pragma unroll
            for (int dd = 0; dd < 4; ++dd)
                vb[dd] = lds_frag8(&Vc[dd * 16 + n16][kc * 32 + quad * 8]);
#pragma unroll
            for (int m = 0; m < 2; ++m)
#pragma unroll
                for (int dd = 0; dd < 4; ++dd)
                    acc_o[m][dd] = __builtin_amdgcn_mfma_f32_16x16x32_bf16(
                        vb[dd], pb[m][kc].v, acc_o[m][dd], 0, 0, 0);
        }

        // ---- stage next pair; issue pair i+2 ----
        if (i + 1 < NP) {
            __syncthreads();               // readers of pair i done
            WRITE_PAIR();                  // regs (pair i+1) -> bufs
            if (i + 2 < NP)
                LOAD_PAIR(i + 2);
            __syncthreads();               // pair i+1 visible
        }
    }
#undef LOAD_PAIR
#undef WRITE_PAIR

    // ---- exact cross-parity combine via LDS scratch (34 f32/lane) ----
    __syncthreads();                       // all compute reads done
    float* scr = (float*)&SMEM[0][0][0][0];
    if (par == 1) {
        float* p = scr + (size_t)(qg * 64 + lane) * 34;
#pragma unroll
        for (int m = 0; m < 2; ++m)
#pragma unroll
            for (int dd = 0; dd < 4; ++dd)
#pragma unroll
                for (int r = 0; r < 4; ++r)
                    p[m * 16 + dd * 4 + r] = acc_o[m][dd][r];
        p[32] = l_p[0];
        p[33] = l_p[1];
    }
    __syncthreads();
    if (par == 0) {
        const float* p = scr + (size_t)(qg * 64 + lane) * 34;
#pragma unroll
        for (int m = 0; m < 2; ++m)
#pragma unroll
            for (int dd = 0; dd < 4; ++dd)
#pragma unroll
                for (int r = 0; r < 4; ++r)
                    acc_o[m][dd][r] += p[m * 16 + dd * 4 + r];
        l_p[0] += p[32];
        l_p[1] += p[33];

        // reduce l across quads (same q = n16), packed O stores
#pragma unroll
        for (int m = 0; m < 2; ++m) {
            float s = l_p[m];
            s += __shfl_xor(s, 16);
            s += __shfl_xor(s, 32);
            const float inv = 1.0f / s;
            const int q = q0 + qg * 32 + m * 16 + n16;
            ushort_t* op = AOb + (size_t)(b * SS + q) * DD + h * HD + quad * 4;
#pragma unroll
            for (int dd = 0; dd < 4; ++dd) {
                uint2 o = { pk2(acc_o[m][dd][0] * inv, acc_o[m][dd][1] * inv),
                            pk2(acc_o[m][dd][2] * inv, acc_o[m][dd][3] * inv) };
                *(uint2*)(op + dd * 16) = o;
            }
        }
    }
}

// ---------------------------------------------------------------------------
// K4: MFMA out-proj (R4 structure).
// out[MM][DD](fp32) = AOb @ Wot^T + bo + HS.  64m x 128n tiles, grid 768.
// ---------------------------------------------------------------------------
__global__ __launch_bounds__(256) void k_out_mfma(const ushort_t* __restrict__ AOb,
                                                  const ushort_t* __restrict__ Wot,
                                                  const float* __restrict__ bo,
                                                  const float* __restrict__ HS,
                                                  float* __restrict__ out)
{
    __shared__ ushort_t As[64][32];    // AOb rows (m)
    __shared__ ushort_t Bs[128][32];   // Wot rows (n)
    const int t = threadIdx.x, lane = t & 63, wave = t >> 6;
    const int n16 = lane & 15, quad = lane >> 4;
    const int wr = wave >> 1, wc = wave & 1;
    const int n0 = blockIdx.x * 128;
    const int m0 = blockIdx.y * 64;

    const int srow = lane >> 2;
    const int scol = (lane & 3) * 8;
    const size_t aoff  = (size_t)(m0 + wave * 16 + srow) * DD + scol;
    const size_t boff0 = (size_t)(n0 + wave * 32 + srow) * DD + scol;
    const size_t boff1 = boff0 + (size_t)16 * DD;
    ushort_t* lA  = &As[wave * 16][0];
    ushort_t* lB0 = &Bs[wave * 32][0];
    ushort_t* lB1 = &Bs[wave * 32 + 16][0];

    f32x4 acc[2][4] = {};
    for (int k0 = 0; k0 < DD; k0 += 32) {
        __syncthreads();
        glds16(AOb + aoff  + k0, lA);
        glds16(Wot + boff0 + k0, lB0);
        glds16(Wot + boff1 + k0, lB1);
        __syncthreads();
        short8 af[2], bf8[4];
#pragma unroll
        for (int i = 0; i < 2; ++i) af[i]  = *(const short8*)&As[wr * 32 + i * 16 + n16][quad * 8];
#pragma unroll
        for (int j = 0; j < 4; ++j) bf8[j] = *(const short8*)&Bs[wc * 64 + j * 16 + n16][quad * 8];
#pragma unroll
        for (int i = 0; i < 2; ++i)
#pragma unroll
            for (int j = 0; j < 4; ++j)
                acc[i][j] = __builtin_amdgcn_mfma_f32_16x16x32_bf16(af[i], bf8[j], acc[i][j], 0, 0, 0);
    }

    const int colb = n0 + wc * 64 + n16;
    float bo4[4];
#pragma unroll
    for (int j = 0; j < 4; ++j) bo4[j] = bo[colb + j * 16];
#pragma unroll
    for (int i = 0; i < 2; ++i) {
#pragma unroll
        for (int r = 0; r < 4; ++r) {
            const int row = m0 + wr * 32 + i * 16 + quad * 4 + r;
            float* op = out + (size_t)row * DD + colb;
            const float* hp = HS + (size_t)row * DD + colb;
#pragma unroll
            for (int j = 0; j < 4; ++j)
                op[j * 16] = acc[i][j][r] + bo4[j] + hp[j * 16];
        }
    }
}

extern "C" void kernel_launch(void* const* d_in, const int* in_sizes, int n_in,
                              void* d_out, int out_size, void* d_ws, size_t ws_size,
                              hipStream_t stream)
{
    const float* HS   = (const float*)d_in[0];
    const float* cosb = (const float*)d_in[1];
    const float* sinb = (const float*)d_in[2];
    const float* Wq   = (const float*)d_in[3];
    const float* Wk   = (const float*)d_in[4];
    const float* Wv   = (const float*)d_in[5];
    const float* Wo   = (const float*)d_in[6];
    const float* bo   = (const float*)d_in[7];
    float* out = (float*)d_out;

    ushort_t* Xbf  = (ushort_t*)d_ws;                  // [MM][DD]
    ushort_t* QKVb = Xbf  + (size_t)MM * DD;           // [MM][QKD]
    ushort_t* AOb  = QKVb + (size_t)MM * QKD;          // [MM][DD]
    ushort_t* Wqt  = AOb  + (size_t)MM * DD;           // [DD][DD]
    ushort_t* Wkt  = Wqt  + (size_t)DD * DD;           // [KVD][DD]
    ushort_t* Wvt  = Wkt  + (size_t)KVD * DD;          // [KVD][DD]
    ushort_t* Wot  = Wvt  + (size_t)KVD * DD;          // [DD][DD]
    ushort_t* VT   = Wot  + (size_t)DD * DD;           // [BB][KVD][SS] (k-permuted)

    const int nprep = NCVT + 2304 + 576 + 576 + 2304;
    k_prep    <<<dim3(nprep), 256, 0, stream>>>(HS, Wq, Wk, Wv, Wo,
                                                Xbf, Wqt, Wkt, Wvt, Wot);
    k_proj    <<<dim3(480 + 192), 256, 0, stream>>>(Xbf, Wqt, Wkt, Wvt,
                                                    cosb, sinb, QKVb, VT);
    k_attn    <<<dim3(SS / 128, HEADS, BB), 512, 0, stream>>>(QKVb, VT, AOb);
    k_out_mfma<<<dim3(DD / 128, MM / 64),   256, 0, stream>>>(AOb, Wot, bo, HS, out);
}

// Round 9
// 256.383 us; speedup vs baseline: 1.1860x; 1.1860x over previous
//
#include <hip/hip_runtime.h>

#define HEADS 24
#define KVH   6
#define HD    64
#define BB    2
#define SS    2048
#define DD    1536
#define KVD   384      // KVH*HD
#define QKD   1920     // DD + KVD (Q|K only; V lives in VT)
#define MM    4096     // BB*SS

typedef unsigned short ushort_t;
typedef __attribute__((ext_vector_type(8))) short short8;
typedef __attribute__((ext_vector_type(4))) short short4v;
typedef __attribute__((ext_vector_type(4))) float f32x4;

__device__ __forceinline__ ushort_t f2bf(float f) {
    union { float f; unsigned u; } v; v.f = f;
    return (ushort_t)((v.u + 0x8000u) >> 16);
}
__device__ __forceinline__ unsigned pk2(float a, float b) {
    union { float f; unsigned u; } x, y; x.f = a; y.f = b;
    return ((x.u + 0x8000u) >> 16) | (((y.u + 0x8000u) >> 16) << 16);
}
// truncation pack (P values: common-mode cancels in softmax)
__device__ __forceinline__ unsigned pk2t(float a, float b) {
    union { float f; unsigned u; } x, y; x.f = a; y.f = b;
    return (x.u >> 16) | (y.u & 0xFFFF0000u);
}
// Schraudolph fast 2^s (±3.5% rel; cancels in p/Σp)
__device__ __forceinline__ float fexp2(float s) {
    float t = fmaf(s, 8388608.0f, 1065055420.0f);   // (127 - 0.0355) * 2^23
    union { int i; float f; } v; v.i = (int)t;
    return v.f;
}
// 16B frag read from an 8B-aligned LDS row: two b64 halves.
__device__ __forceinline__ short8 lds_frag8(const ushort_t* p) {
    short4v lo = *(const short4v*)p;
    short4v hi = *(const short4v*)(p + 4);
    return __builtin_shufflevector(lo, hi, 0, 1, 2, 3, 4, 5, 6, 7);
}
// async global->LDS, 16B per lane; lds ptr must be wave-uniform base.
__device__ __forceinline__ void glds16(const void* g, void* l) {
    __builtin_amdgcn_global_load_lds(
        (const __attribute__((address_space(1))) void*)g,
        (__attribute__((address_space(3))) void*)l, 16, 0, 0);
}

// ---------------------------------------------------------------------------
// K0: fused preprocessing — cvt X + 4x weight transpose-convert.
// ---------------------------------------------------------------------------
__device__ __forceinline__ void tconv_body(const float* __restrict__ in,
                                           ushort_t* __restrict__ out,
                                           int R, int C, int cb, int rb)
{
    __shared__ ushort_t tile[32][33];
    const int tx = threadIdx.x & 31, ty = threadIdx.x >> 5;
    const int c0 = cb * 32, r0 = rb * 32;
#pragma unroll
    for (int i = 0; i < 4; ++i)
        tile[ty + i * 8][tx] = f2bf(in[(size_t)(r0 + ty + i * 8) * C + c0 + tx]);
    __syncthreads();
#pragma unroll
    for (int i = 0; i < 4; ++i)
        out[(size_t)(c0 + ty + i * 8) * R + r0 + tx] = tile[tx][ty + i * 8];
}

#define NCVT (MM * DD / 4 / 256)     // 6144
__global__ __launch_bounds__(256) void k_prep(const float* __restrict__ HS,
                                              const float* __restrict__ Wq,
                                              const float* __restrict__ Wk,
                                              const float* __restrict__ Wv,
                                              const float* __restrict__ Wo,
                                              ushort_t* __restrict__ Xbf,
                                              ushort_t* __restrict__ Wqt,
                                              ushort_t* __restrict__ Wkt,
                                              ushort_t* __restrict__ Wvt,
                                              ushort_t* __restrict__ Wot)
{
    int bid = blockIdx.x;
    if (bid < NCVT) {
        int i = bid * 256 + threadIdx.x;
        float4 v = ((const float4*)HS)[i];
        uint2 o = { pk2(v.x, v.y), pk2(v.z, v.w) };
        ((uint2*)Xbf)[i] = o;
        return;
    }
    bid -= NCVT;
    if (bid < 2304) { tconv_body(Wq, Wqt, DD, DD,  bid % 48, bid / 48); return; }
    bid -= 2304;
    if (bid < 576)  { tconv_body(Wk, Wkt, DD, KVD, bid % 12, bid / 12); return; }
    bid -= 576;
    if (bid < 576)  { tconv_body(Wv, Wvt, DD, KVD, bid % 12, bid / 12); return; }
    bid -= 576;
    tconv_body(Wo, Wot, DD, DD, bid % 48, bid / 48);
}

// ---------------------------------------------------------------------------
// K1: fused projection dispatch (R4 structure).
//   bid <  480 : Q|K projection, 128x128 tiles + RoPE + Q-scale
//   bid >= 480 : V^T GEMM -> VT, k-PERMUTED slot map
//                s = 32*kc + 8*quad + 2*r + j4 <-> tok = 32*kc+16*j4+4*quad+r
// ---------------------------------------------------------------------------
__global__ __launch_bounds__(256) void k_proj(const ushort_t* __restrict__ Xbf,
                                              const ushort_t* __restrict__ Wqt,
                                              const ushort_t* __restrict__ Wkt,
                                              const ushort_t* __restrict__ Wvt,
                                              const float* __restrict__ cosb,
                                              const float* __restrict__ sinb,
                                              ushort_t* __restrict__ QKVb,
                                              ushort_t* __restrict__ VT)
{
    __shared__ ushort_t As[128][32];
    __shared__ ushort_t Bs[128][32];
    const int t = threadIdx.x, lane = t & 63, wave = t >> 6;
    const int n16 = lane & 15, quad = lane >> 4;
    const int wr = wave >> 1, wc = wave & 1;
    const int srow = lane >> 2;
    const int scol = (lane & 3) * 8;

    if (blockIdx.x < 480) {
        // ---------------- Q|K projection ----------------
        const int nt = blockIdx.x % 15;
        const int n0 = nt * 128;
        const int m0 = (blockIdx.x / 15) * 128;
        const ushort_t* Bt; int nl, isq;
        if (nt < 12) { Bt = Wqt; nl = n0;      isq = 1; }
        else         { Bt = Wkt; nl = n0 - DD; isq = 0; }

        const size_t aoff0 = (size_t)(m0 + wave * 16 + srow) * DD + scol;
        const size_t aoff1 = (size_t)(m0 + (wave + 4) * 16 + srow) * DD + scol;
        const size_t boff0 = (size_t)(nl + wave * 16 + srow) * DD + scol;
        const size_t boff1 = (size_t)(nl + (wave + 4) * 16 + srow) * DD + scol;
        ushort_t* lA0 = &As[wave * 16][0];
        ushort_t* lA1 = &As[(wave + 4) * 16][0];
        ushort_t* lB0 = &Bs[wave * 16][0];
        ushort_t* lB1 = &Bs[(wave + 4) * 16][0];

        f32x4 acc[4][4] = {};
        for (int k0 = 0; k0 < DD; k0 += 32) {
            __syncthreads();
            glds16(Xbf + aoff0 + k0, lA0);
            glds16(Xbf + aoff1 + k0, lA1);
            glds16(Bt  + boff0 + k0, lB0);
            glds16(Bt  + boff1 + k0, lB1);
            __syncthreads();
            short8 af[4], bf8[4];
#pragma unroll
            for (int i = 0; i < 4; ++i) af[i]  = *(const short8*)&As[wr * 64 + i * 16 + n16][quad * 8];
#pragma unroll
            for (int j = 0; j < 4; ++j) bf8[j] = *(const short8*)&Bs[wc * 64 + j * 16 + n16][quad * 8];
#pragma unroll
            for (int i = 0; i < 4; ++i)
#pragma unroll
                for (int j = 0; j < 4; ++j)
                    acc[i][j] = __builtin_amdgcn_mfma_f32_16x16x32_bf16(af[i], bf8[j], acc[i][j], 0, 0, 0);
        }

        const float QSC = 0.18033688011112042f;   // 0.125 * log2(e)
#pragma unroll
        for (int i = 0; i < 4; ++i) {
#pragma unroll
            for (int r = 0; r < 4; ++r) {
                const int row = m0 + wr * 64 + i * 16 + quad * 4 + r;
                ushort_t* outp = QKVb + (size_t)row * QKD + n0 + wc * 64 + n16;
                float v0 = acc[i][0][r], v1 = acc[i][1][r];
                float v2 = acc[i][2][r], v3 = acc[i][3][r];
                {   // partial RoPE on head dims 0..31 (Q and K)
                    const int s = row & (SS - 1);
                    float c0 = cosb[s * 32 + n16],      s0 = sinb[s * 32 + n16];
                    float c1 = cosb[s * 32 + 16 + n16], s1 = sinb[s * 32 + 16 + n16];
                    float nr = v0 * c0 - v1 * s0;
                    float ni = v1 * c1 + v0 * s1;
                    v0 = nr; v1 = ni;
                }
                if (isq) { v0 *= QSC; v1 *= QSC; v2 *= QSC; v3 *= QSC; }
                outp[0]  = f2bf(v0);
                outp[16] = f2bf(v1);
                outp[32] = f2bf(v2);
                outp[48] = f2bf(v3);
            }
        }
    } else {
        // ---------------- V^T GEMM (k-permuted epilogue) ----------------
        const int vb = blockIdx.x - 480;
        const int n0 = (vb & 31) * 128;    // tokens
        const int m0 = (vb >> 5) * 64;     // channels c

        const size_t aoff  = (size_t)(m0 + wave * 16 + srow) * DD + scol;
        const size_t boff0 = (size_t)(n0 + wave * 32 + srow) * DD + scol;
        const size_t boff1 = boff0 + (size_t)16 * DD;
        ushort_t* lA  = &As[wave * 16][0];
        ushort_t* lB0 = &Bs[wave * 32][0];
        ushort_t* lB1 = &Bs[wave * 32 + 16][0];

        f32x4 acc[2][4] = {};
        for (int k0 = 0; k0 < DD; k0 += 32) {
            __syncthreads();
            glds16(Wvt + aoff  + k0, lA);
            glds16(Xbf + boff0 + k0, lB0);
            glds16(Xbf + boff1 + k0, lB1);
            __syncthreads();
            short8 af[2], bf8[4];
#pragma unroll
            for (int i = 0; i < 2; ++i) af[i]  = *(const short8*)&As[wr * 32 + i * 16 + n16][quad * 8];
#pragma unroll
            for (int j = 0; j < 4; ++j) bf8[j] = *(const short8*)&Bs[wc * 64 + j * 16 + n16][quad * 8];
#pragma unroll
            for (int i = 0; i < 2; ++i)
#pragma unroll
                for (int j = 0; j < 4; ++j)
                    acc[i][j] = __builtin_amdgcn_mfma_f32_16x16x32_bf16(af[i], bf8[j], acc[i][j], 0, 0, 0);
        }

        const int b = n0 >> 11;            // token tile never straddles batch
        const int s0 = 8 * (n16 >> 2) + 2 * (n16 & 3);
#pragma unroll
        for (int i = 0; i < 2; ++i)
#pragma unroll
            for (int r = 0; r < 4; ++r) {
                const int c = m0 + wr * 32 + i * 16 + quad * 4 + r;
                ushort_t* op = VT + ((size_t)b * KVD + c) * SS +
                               (n0 & (SS - 1)) + wc * 64 + s0;
                *(unsigned*)op        = pk2(acc[i][0][r], acc[i][1][r]);
                *(unsigned*)(op + 32) = pk2(acc[i][2][r], acc[i][3][r]);
            }
    }
}

// ---------------------------------------------------------------------------
// K3: MFMA bf16 flash attention — swapped QK^T, in-register P, fast-exp2.
// ROUND 9: R8's parity split (4 q-groups x 32q x 2 k-parities) with the
// REGISTER SPILL FIXED.  R8's __launch_bounds__(512,4) capped VGPRs below
// the ~120 the m=2 kernel needs live (sT 32 + acc_o 32 + qf 8 + prefetch 16
// + addressing) -> spill to scratch -> WRITE_SIZE 12 -> 132 MB, 147us.
// (512,2) caps at 256: no spill, expected ~110-130 VGPR -> 4 waves/SIMD ->
// 2 blocks/CU = 16 waves/CU (R7-level TLP) with HALF R7's DS-read demand
// (4096 vs 8192 b64/block).  Exact cross-parity combine (associative: no
// max-tracking) via LDS scratch at the end.
// ---------------------------------------------------------------------------
__global__ __launch_bounds__(512, 2) void k_attn(const ushort_t* __restrict__ QKVb,
                                                 const ushort_t* __restrict__ VT,
                                                 ushort_t* __restrict__ AOb)
{
    // one contiguous block: [0]=K, [1]=V; inner index = parity buffer.
    __shared__ __align__(16) ushort_t SMEM[2][2][64][76];

    const int t    = threadIdx.x;
    const int wave = t >> 6;          // 0..7
    const int qg   = wave & 3;        // q-group (32q each)
    const int par  = wave >> 2;       // k-parity this wave computes
    const int quad = (t >> 4) & 3;
    const int n16  = t & 15;
    const int lane = t & 63;
    const int q0   = blockIdx.x * 128;
    const int h    = blockIdx.y;
    const int b    = blockIdx.z;
    const int kh   = h >> 2;

    // staging role: thread stages tile-parity ps (independent of compute par)
    const int ps = t >> 8;            // 0 or 1
    const int tt = t & 255;
    const int sr = tt >> 2;           // 0..63 staging row
    const int sc = (tt & 3) * 8;      // K staging col
    const int vc = (tt & 3) * 16;     // V staging col

    // loop-invariant Q frags (pre-scaled by 0.125*log2e)
    short8 qf[2][2];
#pragma unroll
    for (int m = 0; m < 2; ++m)
#pragma unroll
        for (int kc = 0; kc < 2; ++kc)
            qf[m][kc] = *(const short8*)(QKVb +
                (size_t)(b * SS + q0 + qg * 32 + m * 16 + n16) * QKD +
                h * HD + kc * 32 + quad * 8);

    float l_p[2] = {};                // per-lane partial row sums (q = n16)
    f32x4 acc_o[2][4] = {};           // C[d][q]: row d = quad*4+r, col q = n16

    const ushort_t* Kbase = QKVb + (size_t)(b * SS) * QKD + DD + kh * HD;
    const ushort_t* Vbase = VT + ((size_t)b * KVD + kh * 64) * SS;

    uint4 kv0, kv1, vv0, vv1;         // prefetch regs: this thread's tile of a pair

#define LOAD_PAIR(I) do {                                                   \
        const int k0s = ((I) * 2 + ps) * 64;                                \
        const ushort_t* Kg = Kbase + (size_t)(k0s + sr) * QKD + sc;         \
        kv0 = *(const uint4*)(Kg);                                          \
        kv1 = *(const uint4*)(Kg + 32);                                     \
        const ushort_t* Vg = Vbase + (size_t)sr * SS + k0s + vc;            \
        vv0 = *(const uint4*)(Vg);                                          \
        vv1 = *(const uint4*)(Vg + 8);                                      \
    } while (0)

#define WRITE_PAIR() do {                                                   \
        *(uint2*)&SMEM[0][ps][sr][sc]      = make_uint2(kv0.x, kv0.y);      \
        *(uint2*)&SMEM[0][ps][sr][sc + 4]  = make_uint2(kv0.z, kv0.w);      \
        *(uint2*)&SMEM[0][ps][sr][sc + 32] = make_uint2(kv1.x, kv1.y);      \
        *(uint2*)&SMEM[0][ps][sr][sc + 36] = make_uint2(kv1.z, kv1.w);      \
        *(uint2*)&SMEM[1][ps][sr][vc]      = make_uint2(vv0.x, vv0.y);      \
        *(uint2*)&SMEM[1][ps][sr][vc + 4]  = make_uint2(vv0.z, vv0.w);      \
        *(uint2*)&SMEM[1][ps][sr][vc + 8]  = make_uint2(vv1.x, vv1.y);      \
        *(uint2*)&SMEM[1][ps][sr][vc + 12] = make_uint2(vv1.z, vv1.w);      \
    } while (0)

    // ---- prologue: pair 0 -> bufs; pair 1 -> regs; barrier ----
    LOAD_PAIR(0);
    WRITE_PAIR();
    LOAD_PAIR(1);
    __syncthreads();

    const int NP = SS / 128;          // 16 pairs of tiles
    for (int i = 0; i < NP; ++i) {
        const ushort_t (*Kc)[76] = SMEM[0][par];
        const ushort_t (*Vc)[76] = SMEM[1][par];

        // ---- swapped QK^T on this wave's tile of the pair ----
        f32x4 sT[2][4] = {};
#pragma unroll
        for (int kc = 0; kc < 2; ++kc) {
            short8 bf[4];
#pragma unroll
            for (int jj = 0; jj < 4; ++jj)
                bf[jj] = lds_frag8(&Kc[jj * 16 + n16][kc * 32 + quad * 8]);
#pragma unroll
            for (int m = 0; m < 2; ++m)
#pragma unroll
                for (int jj = 0; jj < 4; ++jj)
                    sT[m][jj] = __builtin_amdgcn_mfma_f32_16x16x32_bf16(
                        bf[jj], qf[m][kc], sT[m][jj], 0, 0, 0);
        }

        // ---- softmax in-register -> PV B-frag words ----
        union PB { unsigned w[4]; short8 v; };
        PB pb[2][2];
#pragma unroll
        for (int m = 0; m < 2; ++m) {
#pragma unroll
            for (int w = 0; w < 4; ++w) {
                float p0 = fexp2(sT[m][0][w]);
                float p1 = fexp2(sT[m][1][w]);
                float p2 = fexp2(sT[m][2][w]);
                float p3 = fexp2(sT[m][3][w]);
                pb[m][0].w[w] = pk2t(p0, p1);
                pb[m][1].w[w] = pk2t(p2, p3);
                l_p[m] += (p0 + p1) + (p2 + p3);
            }
        }

        // ---- PV ----
#pragma unroll
        for (int kc = 0; kc < 2; ++kc) {
            short8 vb[4];
#pragma unroll
            for (int dd = 0; dd < 4; ++dd)
                vb[dd] = lds_frag8(&Vc[dd * 16 + n16][kc * 32 + quad * 8]);
#pragma unroll
            for (int m = 0; m < 2; ++m)
#pragma unroll
                for (int dd = 0; dd < 4; ++dd)
                    acc_o[m][dd] = __builtin_amdgcn_mfma_f32_16x16x32_bf16(
                        vb[dd], pb[m][kc].v, acc_o[m][dd], 0, 0, 0);
        }

        // ---- stage next pair; issue pair i+2 ----
        if (i + 1 < NP) {
            __syncthreads();               // readers of pair i done
            WRITE_PAIR();                  // regs (pair i+1) -> bufs
            if (i + 2 < NP)
                LOAD_PAIR(i + 2);
            __syncthreads();               // pair i+1 visible
        }
    }
#undef LOAD_PAIR
#undef WRITE_PAIR

    // ---- exact cross-parity combine via LDS scratch (34 f32/lane) ----
    __syncthreads();                       // all compute reads done
    float* scr = (float*)&SMEM[0][0][0][0];
    if (par == 1) {
        float* p = scr + (size_t)(qg * 64 + lane) * 34;
#pragma unroll
        for (int m = 0; m < 2; ++m)
#pragma unroll
            for (int dd = 0; dd < 4; ++dd)
#pragma unroll
                for (int r = 0; r < 4; ++r)
                    p[m * 16 + dd * 4 + r] = acc_o[m][dd][r];
        p[32] = l_p[0];
        p[33] = l_p[1];
    }
    __syncthreads();
    if (par == 0) {
        const float* p = scr + (size_t)(qg * 64 + lane) * 34;
#pragma unroll
        for (int m = 0; m < 2; ++m)
#pragma unroll
            for (int dd = 0; dd < 4; ++dd)
#pragma unroll
                for (int r = 0; r < 4; ++r)
                    acc_o[m][dd][r] += p[m * 16 + dd * 4 + r];
        l_p[0] += p[32];
        l_p[1] += p[33];

        // reduce l across quads (same q = n16), packed O stores
#pragma unroll
        for (int m = 0; m < 2; ++m) {
            float s = l_p[m];
            s += __shfl_xor(s, 16);
            s += __shfl_xor(s, 32);
            const float inv = 1.0f / s;
            const int q = q0 + qg * 32 + m * 16 + n16;
            ushort_t* op = AOb + (size_t)(b * SS + q) * DD + h * HD + quad * 4;
#pragma unroll
            for (int dd = 0; dd < 4; ++dd) {
                uint2 o = { pk2(acc_o[m][dd][0] * inv, acc_o[m][dd][1] * inv),
                            pk2(acc_o[m][dd][2] * inv, acc_o[m][dd][3] * inv) };
                *(uint2*)(op + dd * 16) = o;
            }
        }
    }
}

// ---------------------------------------------------------------------------
// K4: MFMA out-proj (R4 structure).
// out[MM][DD](fp32) = AOb @ Wot^T + bo + HS.  64m x 128n tiles, grid 768.
// ---------------------------------------------------------------------------
__global__ __launch_bounds__(256) void k_out_mfma(const ushort_t* __restrict__ AOb,
                                                  const ushort_t* __restrict__ Wot,
                                                  const float* __restrict__ bo,
                                                  const float* __restrict__ HS,
                                                  float* __restrict__ out)
{
    __shared__ ushort_t As[64][32];    // AOb rows (m)
    __shared__ ushort_t Bs[128][32];   // Wot rows (n)
    const int t = threadIdx.x, lane = t & 63, wave = t >> 6;
    const int n16 = lane & 15, quad = lane >> 4;
    const int wr = wave >> 1, wc = wave & 1;
    const int n0 = blockIdx.x * 128;
    const int m0 = blockIdx.y * 64;

    const int srow = lane >> 2;
    const int scol = (lane & 3) * 8;
    const size_t aoff  = (size_t)(m0 + wave * 16 + srow) * DD + scol;
    const size_t boff0 = (size_t)(n0 + wave * 32 + srow) * DD + scol;
    const size_t boff1 = boff0 + (size_t)16 * DD;
    ushort_t* lA  = &As[wave * 16][0];
    ushort_t* lB0 = &Bs[wave * 32][0];
    ushort_t* lB1 = &Bs[wave * 32 + 16][0];

    f32x4 acc[2][4] = {};
    for (int k0 = 0; k0 < DD; k0 += 32) {
        __syncthreads();
        glds16(AOb + aoff  + k0, lA);
        glds16(Wot + boff0 + k0, lB0);
        glds16(Wot + boff1 + k0, lB1);
        __syncthreads();
        short8 af[2], bf8[4];
#pragma unroll
        for (int i = 0; i < 2; ++i) af[i]  = *(const short8*)&As[wr * 32 + i * 16 + n16][quad * 8];
#pragma unroll
        for (int j = 0; j < 4; ++j) bf8[j] = *(const short8*)&Bs[wc * 64 + j * 16 + n16][quad * 8];
#pragma unroll
        for (int i = 0; i < 2; ++i)
#pragma unroll
            for (int j = 0; j < 4; ++j)
                acc[i][j] = __builtin_amdgcn_mfma_f32_16x16x32_bf16(af[i], bf8[j], acc[i][j], 0, 0, 0);
    }

    const int colb = n0 + wc * 64 + n16;
    float bo4[4];
#pragma unroll
    for (int j = 0; j < 4; ++j) bo4[j] = bo[colb + j * 16];
#pragma unroll
    for (int i = 0; i < 2; ++i) {
#pragma unroll
        for (int r = 0; r < 4; ++r) {
            const int row = m0 + wr * 32 + i * 16 + quad * 4 + r;
            float* op = out + (size_t)row * DD + colb;
            const float* hp = HS + (size_t)row * DD + colb;
#pragma unroll
            for (int j = 0; j < 4; ++j)
                op[j * 16] = acc[i][j][r] + bo4[j] + hp[j * 16];
        }
    }
}

extern "C" void kernel_launch(void* const* d_in, const int* in_sizes, int n_in,
                              void* d_out, int out_size, void* d_ws, size_t ws_size,
                              hipStream_t stream)
{
    const float* HS   = (const float*)d_in[0];
    const float* cosb = (const float*)d_in[1];
    const float* sinb = (const float*)d_in[2];
    const float* Wq   = (const float*)d_in[3];
    const float* Wk   = (const float*)d_in[4];
    const float* Wv   = (const float*)d_in[5];
    const float* Wo   = (const float*)d_in[6];
    const float* bo   = (const float*)d_in[7];
    float* out = (float*)d_out;

    ushort_t* Xbf  = (ushort_t*)d_ws;                  // [MM][DD]
    ushort_t* QKVb = Xbf  + (size_t)MM * DD;           // [MM][QKD]
    ushort_t* AOb  = QKVb + (size_t)MM * QKD;          // [MM][DD]
    ushort_t* Wqt  = AOb  + (size_t)MM * DD;           // [DD][DD]
    ushort_t* Wkt  = Wqt  + (size_t)DD * DD;           // [KVD][DD]
    ushort_t* Wvt  = Wkt  + (size_t)KVD * DD;          // [KVD][DD]
    ushort_t* Wot  = Wvt  + (size_t)KVD * DD;          // [DD][DD]
    ushort_t* VT   = Wot  + (size_t)DD * DD;           // [BB][KVD][SS] (k-permuted)

    const int nprep = NCVT + 2304 + 576 + 576 + 2304;
    k_prep    <<<dim3(nprep), 256, 0, stream>>>(HS, Wq, Wk, Wv, Wo,
                                                Xbf, Wqt, Wkt, Wvt, Wot);
    k_proj    <<<dim3(480 + 192), 256, 0, stream>>>(Xbf, Wqt, Wkt, Wvt,
                                                    cosb, sinb, QKVb, VT);
    k_attn    <<<dim3(SS / 128, HEADS, BB), 512, 0, stream>>>(QKVb, VT, AOb);
    k_out_mfma<<<dim3(DD / 128, MM / 64),   256, 0, stream>>>(AOb, Wot, bo, HS, out);
}

// Round 10
// 250.143 us; speedup vs baseline: 1.2156x; 1.0249x over previous
//
#include <hip/hip_runtime.h>

#define HEADS 24
#define KVH   6
#define HD    64
#define BB    2
#define SS    2048
#define DD    1536
#define KVD   384      // KVH*HD
#define QKD   1920     // DD + KVD (Q|K only; V lives in VT)
#define MM    4096     // BB*SS

typedef unsigned short ushort_t;
typedef __attribute__((ext_vector_type(8))) short short8;
typedef __attribute__((ext_vector_type(4))) short short4v;
typedef __attribute__((ext_vector_type(4))) float f32x4;

__device__ __forceinline__ ushort_t f2bf(float f) {
    union { float f; unsigned u; } v; v.f = f;
    return (ushort_t)((v.u + 0x8000u) >> 16);
}
__device__ __forceinline__ unsigned pk2(float a, float b) {
    union { float f; unsigned u; } x, y; x.f = a; y.f = b;
    return ((x.u + 0x8000u) >> 16) | (((y.u + 0x8000u) >> 16) << 16);
}
// truncation pack (P values: common-mode cancels in softmax)
__device__ __forceinline__ unsigned pk2t(float a, float b) {
    union { float f; unsigned u; } x, y; x.f = a; y.f = b;
    return (x.u >> 16) | (y.u & 0xFFFF0000u);
}
// Schraudolph fast 2^s (±3.5% rel; cancels in p/Σp)
__device__ __forceinline__ float fexp2(float s) {
    float t = fmaf(s, 8388608.0f, 1065055420.0f);   // (127 - 0.0355) * 2^23
    union { int i; float f; } v; v.i = (int)t;
    return v.f;
}
// 16B frag read from an 8B-aligned LDS row: two b64 halves.
__device__ __forceinline__ short8 lds_frag8(const ushort_t* p) {
    short4v lo = *(const short4v*)p;
    short4v hi = *(const short4v*)(p + 4);
    return __builtin_shufflevector(lo, hi, 0, 1, 2, 3, 4, 5, 6, 7);
}
// async global->LDS, 16B per lane; lds ptr must be wave-uniform base.
__device__ __forceinline__ void glds16(const void* g, void* l) {
    __builtin_amdgcn_global_load_lds(
        (const __attribute__((address_space(1))) void*)g,
        (__attribute__((address_space(3))) void*)l, 16, 0, 0);
}

// ---------------------------------------------------------------------------
// K0: fused preprocessing — cvt X + 4x weight transpose-convert.
// ---------------------------------------------------------------------------
__device__ __forceinline__ void tconv_body(const float* __restrict__ in,
                                           ushort_t* __restrict__ out,
                                           int R, int C, int cb, int rb)
{
    __shared__ ushort_t tile[32][33];
    const int tx = threadIdx.x & 31, ty = threadIdx.x >> 5;
    const int c0 = cb * 32, r0 = rb * 32;
#pragma unroll
    for (int i = 0; i < 4; ++i)
        tile[ty + i * 8][tx] = f2bf(in[(size_t)(r0 + ty + i * 8) * C + c0 + tx]);
    __syncthreads();
#pragma unroll
    for (int i = 0; i < 4; ++i)
        out[(size_t)(c0 + ty + i * 8) * R + r0 + tx] = tile[tx][ty + i * 8];
}

#define NCVT (MM * DD / 4 / 256)     // 6144
__global__ __launch_bounds__(256) void k_prep(const float* __restrict__ HS,
                                              const float* __restrict__ Wq,
                                              const float* __restrict__ Wk,
                                              const float* __restrict__ Wv,
                                              const float* __restrict__ Wo,
                                              ushort_t* __restrict__ Xbf,
                                              ushort_t* __restrict__ Wqt,
                                              ushort_t* __restrict__ Wkt,
                                              ushort_t* __restrict__ Wvt,
                                              ushort_t* __restrict__ Wot)
{
    int bid = blockIdx.x;
    if (bid < NCVT) {
        int i = bid * 256 + threadIdx.x;
        float4 v = ((const float4*)HS)[i];
        uint2 o = { pk2(v.x, v.y), pk2(v.z, v.w) };
        ((uint2*)Xbf)[i] = o;
        return;
    }
    bid -= NCVT;
    if (bid < 2304) { tconv_body(Wq, Wqt, DD, DD,  bid % 48, bid / 48); return; }
    bid -= 2304;
    if (bid < 576)  { tconv_body(Wk, Wkt, DD, KVD, bid % 12, bid / 12); return; }
    bid -= 576;
    if (bid < 576)  { tconv_body(Wv, Wvt, DD, KVD, bid % 12, bid / 12); return; }
    bid -= 576;
    tconv_body(Wo, Wot, DD, DD, bid % 48, bid / 48);
}

// ---------------------------------------------------------------------------
// K1: fused projection dispatch.
// ROUND 10 change (both branches): BK 32 -> 64 with XOR chunk-swizzle.
//   The 2-barrier loop's critical path is the per-step vmcnt(0) drain at the
//   barrier (fixed ~400cy regardless of BK) — BK=64 halves drain events
//   (48 -> 24 for K=1536) at identical MFMA/staging instruction totals.
//   128B rows would be a 16-way bank conflict (guide G4), so LDS chunk c of
//   row r holds global chunk c^(r&7): staging pre-swizzles the GLOBAL source
//   column (glds16 dest stays linear), reads XOR the chunk — both-sides
//   involution, bit-exact.  Read rows are === n16 (mod 8) in all bodies, so
//   lanes spread over 8 chunks -> ~2-way (free).  LDS 32 KB -> 5 blocks/CU.
//   bid <  480 : Q|K projection, 128x128 tiles + RoPE + Q-scale
//   bid >= 480 : V^T GEMM -> VT, k-PERMUTED slot map
//                s = 32*kc + 8*quad + 2*r + j4 <-> tok = 32*kc+16*j4+4*quad+r
// ---------------------------------------------------------------------------
__global__ __launch_bounds__(256) void k_proj(const ushort_t* __restrict__ Xbf,
                                              const ushort_t* __restrict__ Wqt,
                                              const ushort_t* __restrict__ Wkt,
                                              const ushort_t* __restrict__ Wvt,
                                              const float* __restrict__ cosb,
                                              const float* __restrict__ sinb,
                                              ushort_t* __restrict__ QKVb,
                                              ushort_t* __restrict__ VT)
{
    __shared__ ushort_t As[128][64];
    __shared__ ushort_t Bs[128][64];
    const int t = threadIdx.x, lane = t & 63, wave = t >> 6;
    const int n16 = lane & 15, quad = lane >> 4;
    const int wr = wave >> 1, wc = wave & 1;
    const int sr8 = lane >> 3;                 // 0..7 staging row-in-wave
    const int swc = ((lane & 7) ^ sr8) * 8;    // pre-swizzled global chunk
    const int cx  = n16 & 7;                   // read-side XOR key

    if (blockIdx.x < 480) {
        // ---------------- Q|K projection ----------------
        const int nt = blockIdx.x % 15;
        const int n0 = nt * 128;
        const int m0 = (blockIdx.x / 15) * 128;
        const ushort_t* Bt; int nl, isq;
        if (nt < 12) { Bt = Wqt; nl = n0;      isq = 1; }
        else         { Bt = Wkt; nl = n0 - DD; isq = 0; }

        f32x4 acc[4][4] = {};
        for (int k0 = 0; k0 < DD; k0 += 64) {
            __syncthreads();
#pragma unroll
            for (int o = 0; o < 128; o += 32) {
                glds16(Xbf + (size_t)(m0 + o + wave * 8 + sr8) * DD + k0 + swc,
                       &As[o + wave * 8][0]);
                glds16(Bt  + (size_t)(nl + o + wave * 8 + sr8) * DD + k0 + swc,
                       &Bs[o + wave * 8][0]);
            }
            __syncthreads();
#pragma unroll
            for (int kc2 = 0; kc2 < 2; ++kc2) {
                const int ch = (((kc2 << 2) | quad) ^ cx) * 8;
                short8 af[4], bf8[4];
#pragma unroll
                for (int i = 0; i < 4; ++i) af[i]  = *(const short8*)&As[wr * 64 + i * 16 + n16][ch];
#pragma unroll
                for (int j = 0; j < 4; ++j) bf8[j] = *(const short8*)&Bs[wc * 64 + j * 16 + n16][ch];
#pragma unroll
                for (int i = 0; i < 4; ++i)
#pragma unroll
                    for (int j = 0; j < 4; ++j)
                        acc[i][j] = __builtin_amdgcn_mfma_f32_16x16x32_bf16(af[i], bf8[j], acc[i][j], 0, 0, 0);
            }
        }

        const float QSC = 0.18033688011112042f;   // 0.125 * log2(e)
#pragma unroll
        for (int i = 0; i < 4; ++i) {
#pragma unroll
            for (int r = 0; r < 4; ++r) {
                const int row = m0 + wr * 64 + i * 16 + quad * 4 + r;
                ushort_t* outp = QKVb + (size_t)row * QKD + n0 + wc * 64 + n16;
                float v0 = acc[i][0][r], v1 = acc[i][1][r];
                float v2 = acc[i][2][r], v3 = acc[i][3][r];
                {   // partial RoPE on head dims 0..31 (Q and K)
                    const int s = row & (SS - 1);
                    float c0 = cosb[s * 32 + n16],      s0 = sinb[s * 32 + n16];
                    float c1 = cosb[s * 32 + 16 + n16], s1 = sinb[s * 32 + 16 + n16];
                    float nr = v0 * c0 - v1 * s0;
                    float ni = v1 * c1 + v0 * s1;
                    v0 = nr; v1 = ni;
                }
                if (isq) { v0 *= QSC; v1 *= QSC; v2 *= QSC; v3 *= QSC; }
                outp[0]  = f2bf(v0);
                outp[16] = f2bf(v1);
                outp[32] = f2bf(v2);
                outp[48] = f2bf(v3);
            }
        }
    } else {
        // ---------------- V^T GEMM (k-permuted epilogue) ----------------
        const int vb = blockIdx.x - 480;
        const int n0 = (vb & 31) * 128;    // tokens
        const int m0 = (vb >> 5) * 64;     // channels c

        f32x4 acc[2][4] = {};
        for (int k0 = 0; k0 < DD; k0 += 64) {
            __syncthreads();
#pragma unroll
            for (int o = 0; o < 64; o += 32)
                glds16(Wvt + (size_t)(m0 + o + wave * 8 + sr8) * DD + k0 + swc,
                       &As[o + wave * 8][0]);
#pragma unroll
            for (int o = 0; o < 128; o += 32)
                glds16(Xbf + (size_t)(n0 + o + wave * 8 + sr8) * DD + k0 + swc,
                       &Bs[o + wave * 8][0]);
            __syncthreads();
#pragma unroll
            for (int kc2 = 0; kc2 < 2; ++kc2) {
                const int ch = (((kc2 << 2) | quad) ^ cx) * 8;
                short8 af[2], bf8[4];
#pragma unroll
                for (int i = 0; i < 2; ++i) af[i]  = *(const short8*)&As[wr * 32 + i * 16 + n16][ch];
#pragma unroll
                for (int j = 0; j < 4; ++j) bf8[j] = *(const short8*)&Bs[wc * 64 + j * 16 + n16][ch];
#pragma unroll
                for (int i = 0; i < 2; ++i)
#pragma unroll
                    for (int j = 0; j < 4; ++j)
                        acc[i][j] = __builtin_amdgcn_mfma_f32_16x16x32_bf16(af[i], bf8[j], acc[i][j], 0, 0, 0);
            }
        }

        const int b = n0 >> 11;            // token tile never straddles batch
        const int s0 = 8 * (n16 >> 2) + 2 * (n16 & 3);
#pragma unroll
        for (int i = 0; i < 2; ++i)
#pragma unroll
            for (int r = 0; r < 4; ++r) {
                const int c = m0 + wr * 32 + i * 16 + quad * 4 + r;
                ushort_t* op = VT + ((size_t)b * KVD + c) * SS +
                               (n0 & (SS - 1)) + wc * 64 + s0;
                *(unsigned*)op        = pk2(acc[i][0][r], acc[i][1][r]);
                *(unsigned*)(op + 32) = pk2(acc[i][2][r], acc[i][3][r]);
            }
    }
}

// ---------------------------------------------------------------------------
// K3: MFMA bf16 flash attention — R7 structure VERBATIM (best measured:
// 76.6us, occupancy 49%, 0 bank conflicts).  512 threads / 8 waves x 16q,
// swapped QK^T, in-register P, fast-exp2, double-buffered Ks/Vs, one
// barrier/tile, prefetch-1 reg staging.  R8/R9 parity-split falsified the
// LDS-issue theory (halved DS reads, no gain) -> structural attn work stops.
// ---------------------------------------------------------------------------
__global__ __launch_bounds__(512, 6) void k_attn(const ushort_t* __restrict__ QKVb,
                                                 const ushort_t* __restrict__ VT,
                                                 ushort_t* __restrict__ AOb)
{
    __shared__ __align__(16) ushort_t Ks[2][64][76];
    __shared__ __align__(16) ushort_t Vs[2][64][76];   // Vs[buf][d][slot]

    const int t    = threadIdx.x;
    const int wave = t >> 6;          // 0..7 -> q-range wave*16
    const int quad = (t >> 4) & 3;
    const int n16  = t & 15;
    const int q0   = blockIdx.x * 128;
    const int h    = blockIdx.y;
    const int b    = blockIdx.z;
    const int kh   = h >> 2;

    const int sr = t >> 3;            // 0..63 staging row (8 lanes/row)
    const int sc = (t & 7) * 8;       // ushort col: 8 lanes x 16B = 128B row

    // loop-invariant Q frags from global (pre-scaled by 0.125*log2e)
    short8 qf[2];
#pragma unroll
    for (int kc = 0; kc < 2; ++kc)
        qf[kc] = *(const short8*)(QKVb +
            (size_t)(b * SS + q0 + wave * 16 + n16) * QKD +
            h * HD + kc * 32 + quad * 8);

    float l_p = 0.0f;                 // per-lane partial row sum (q = n16)
    f32x4 acc_o[4] = {};              // C[d][q]: row d = quad*4+r, col q = n16

    const ushort_t* Kbase = QKVb + (size_t)(b * SS) * QKD + DD + kh * HD;
    const ushort_t* Vbase = VT + ((size_t)b * KVD + kh * 64) * SS;

    uint4 kv, vv;                     // prefetch registers (one tile)

#define LOAD_TILE(K0) do {                                                  \
        kv = *(const uint4*)(Kbase + (size_t)((K0) + sr) * QKD + sc);       \
        vv = *(const uint4*)(Vbase + (size_t)sr * SS + (K0) + sc);          \
    } while (0)

#define WRITE_BUF(BI) do {                                                  \
        *(uint2*)&Ks[BI][sr][sc]     = make_uint2(kv.x, kv.y);              \
        *(uint2*)&Ks[BI][sr][sc + 4] = make_uint2(kv.z, kv.w);              \
        *(uint2*)&Vs[BI][sr][sc]     = make_uint2(vv.x, vv.y);              \
        *(uint2*)&Vs[BI][sr][sc + 4] = make_uint2(vv.z, vv.w);              \
    } while (0)

    // ---- prologue: tile 0 -> buf0; issue tile 1; barrier ----
    LOAD_TILE(0);
    WRITE_BUF(0);
    LOAD_TILE(64);
    __syncthreads();

    const int NT = SS / 64;
    for (int kt = 0; kt < NT; ++kt) {
        const int cur = kt & 1;
        const ushort_t (*Kc)[76] = Ks[cur];
        const ushort_t (*Vc)[76] = Vs[cur];

        // ---- swapped QK^T: S^T[64k][16q] per wave ----
        f32x4 sT[4] = {};
#pragma unroll
        for (int kc = 0; kc < 2; ++kc) {
            short8 bf[4];
#pragma unroll
            for (int jj = 0; jj < 4; ++jj)
                bf[jj] = lds_frag8(&Kc[jj * 16 + n16][kc * 32 + quad * 8]);
#pragma unroll
            for (int jj = 0; jj < 4; ++jj)
                sT[jj] = __builtin_amdgcn_mfma_f32_16x16x32_bf16(
                    bf[jj], qf[kc], sT[jj], 0, 0, 0);
        }

        // ---- softmax fully in-register: pb[kc] = PV B-frag words ----
        union PB { unsigned w[4]; short8 v; };
        PB pb[2];
#pragma unroll
        for (int w = 0; w < 4; ++w) {
            float p0 = fexp2(sT[0][w]);
            float p1 = fexp2(sT[1][w]);
            float p2 = fexp2(sT[2][w]);
            float p3 = fexp2(sT[3][w]);
            pb[0].w[w] = pk2t(p0, p1);   // slots j=2w,2w+1 of kc=0
            pb[1].w[w] = pk2t(p2, p3);   // slots j=2w,2w+1 of kc=1
            l_p += (p0 + p1) + (p2 + p3);
        }

        // ---- PV: acc_o[dd] += V^T-frag x P^T-frag ----
#pragma unroll
        for (int kc = 0; kc < 2; ++kc) {
            short8 vb[4];
#pragma unroll
            for (int dd = 0; dd < 4; ++dd)
                vb[dd] = lds_frag8(&Vc[dd * 16 + n16][kc * 32 + quad * 8]);
#pragma unroll
            for (int dd = 0; dd < 4; ++dd)
                acc_o[dd] = __builtin_amdgcn_mfma_f32_16x16x32_bf16(
                    vb[dd], pb[kc].v, acc_o[dd], 0, 0, 0);
        }

        // ---- stage next tile into the other buffer; issue tile kt+2 ----
        if (kt + 1 < NT) {
            WRITE_BUF(cur ^ 1);            // vmcnt wait lands here (hidden)
            if (kt + 2 < NT)
                LOAD_TILE((kt + 2) * 64);
            __syncthreads();
        }
    }
#undef LOAD_TILE
#undef WRITE_BUF

    // ---- epilogue: reduce l across quads (same q = n16), packed O stores --
    {
        float s = l_p;
        s += __shfl_xor(s, 16);
        s += __shfl_xor(s, 32);
        const float inv = 1.0f / s;
        const int q = q0 + wave * 16 + n16;
        ushort_t* op = AOb + (size_t)(b * SS + q) * DD + h * HD + quad * 4;
#pragma unroll
        for (int dd = 0; dd < 4; ++dd) {
            uint2 o = { pk2(acc_o[dd][0] * inv, acc_o[dd][1] * inv),
                        pk2(acc_o[dd][2] * inv, acc_o[dd][3] * inv) };
            *(uint2*)(op + dd * 16) = o;
        }
    }
}

// ---------------------------------------------------------------------------
// K4: MFMA out-proj.  out[MM][DD](fp32) = AOb @ Wot^T + bo + HS.
// ROUND 10: same BK=64 + XOR chunk-swizzle as k_proj.  LDS 24 KB.
// ---------------------------------------------------------------------------
__global__ __launch_bounds__(256) void k_out_mfma(const ushort_t* __restrict__ AOb,
                                                  const ushort_t* __restrict__ Wot,
                                                  const float* __restrict__ bo,
                                                  const float* __restrict__ HS,
                                                  float* __restrict__ out)
{
    __shared__ ushort_t As[64][64];    // AOb rows (m)
    __shared__ ushort_t Bs[128][64];   // Wot rows (n)
    const int t = threadIdx.x, lane = t & 63, wave = t >> 6;
    const int n16 = lane & 15, quad = lane >> 4;
    const int wr = wave >> 1, wc = wave & 1;
    const int n0 = blockIdx.x * 128;
    const int m0 = blockIdx.y * 64;

    const int sr8 = lane >> 3;
    const int swc = ((lane & 7) ^ sr8) * 8;
    const int cx  = n16 & 7;

    f32x4 acc[2][4] = {};
    for (int k0 = 0; k0 < DD; k0 += 64) {
        __syncthreads();
#pragma unroll
        for (int o = 0; o < 64; o += 32)
            glds16(AOb + (size_t)(m0 + o + wave * 8 + sr8) * DD + k0 + swc,
                   &As[o + wave * 8][0]);
#pragma unroll
        for (int o = 0; o < 128; o += 32)
            glds16(Wot + (size_t)(n0 + o + wave * 8 + sr8) * DD + k0 + swc,
                   &Bs[o + wave * 8][0]);
        __syncthreads();
#pragma unroll
        for (int kc2 = 0; kc2 < 2; ++kc2) {
            const int ch = (((kc2 << 2) | quad) ^ cx) * 8;
            short8 af[2], bf8[4];
#pragma unroll
            for (int i = 0; i < 2; ++i) af[i]  = *(const short8*)&As[wr * 32 + i * 16 + n16][ch];
#pragma unroll
            for (int j = 0; j < 4; ++j) bf8[j] = *(const short8*)&Bs[wc * 64 + j * 16 + n16][ch];
#pragma unroll
            for (int i = 0; i < 2; ++i)
#pragma unroll
                for (int j = 0; j < 4; ++j)
                    acc[i][j] = __builtin_amdgcn_mfma_f32_16x16x32_bf16(af[i], bf8[j], acc[i][j], 0, 0, 0);
        }
    }

    const int colb = n0 + wc * 64 + n16;
    float bo4[4];
#pragma unroll
    for (int j = 0; j < 4; ++j) bo4[j] = bo[colb + j * 16];
#pragma unroll
    for (int i = 0; i < 2; ++i) {
#pragma unroll
        for (int r = 0; r < 4; ++r) {
            const int row = m0 + wr * 32 + i * 16 + quad * 4 + r;
            float* op = out + (size_t)row * DD + colb;
            const float* hp = HS + (size_t)row * DD + colb;
#pragma unroll
            for (int j = 0; j < 4; ++j)
                op[j * 16] = acc[i][j][r] + bo4[j] + hp[j * 16];
        }
    }
}

extern "C" void kernel_launch(void* const* d_in, const int* in_sizes, int n_in,
                              void* d_out, int out_size, void* d_ws, size_t ws_size,
                              hipStream_t stream)
{
    const float* HS   = (const float*)d_in[0];
    const float* cosb = (const float*)d_in[1];
    const float* sinb = (const float*)d_in[2];
    const float* Wq   = (const float*)d_in[3];
    const float* Wk   = (const float*)d_in[4];
    const float* Wv   = (const float*)d_in[5];
    const float* Wo   = (const float*)d_in[6];
    const float* bo   = (const float*)d_in[7];
    float* out = (float*)d_out;

    ushort_t* Xbf  = (ushort_t*)d_ws;                  // [MM][DD]
    ushort_t* QKVb = Xbf  + (size_t)MM * DD;           // [MM][QKD]
    ushort_t* AOb  = QKVb + (size_t)MM * QKD;          // [MM][DD]
    ushort_t* Wqt  = AOb  + (size_t)MM * DD;           // [DD][DD]
    ushort_t* Wkt  = Wqt  + (size_t)DD * DD;           // [KVD][DD]
    ushort_t* Wvt  = Wkt  + (size_t)KVD * DD;          // [KVD][DD]
    ushort_t* Wot  = Wvt  + (size_t)KVD * DD;          // [DD][DD]
    ushort_t* VT   = Wot  + (size_t)DD * DD;           // [BB][KVD][SS] (k-permuted)

    const int nprep = NCVT + 2304 + 576 + 576 + 2304;
    k_prep    <<<dim3(nprep), 256, 0, stream>>>(HS, Wq, Wk, Wv, Wo,
                                                Xbf, Wqt, Wkt, Wvt, Wot);
    k_proj    <<<dim3(480 + 192), 256, 0, stream>>>(Xbf, Wqt, Wkt, Wvt,
                                                    cosb, sinb, QKVb, VT);
    k_attn    <<<dim3(SS / 128, HEADS, BB), 512, 0, stream>>>(QKVb, VT, AOb);
    k_out_mfma<<<dim3(DD / 128, MM / 64),   256, 0, stream>>>(AOb, Wot, bo, HS, out);
}

// Round 11
// 249.099 us; speedup vs baseline: 1.2207x; 1.0042x over previous
//
#include <hip/hip_runtime.h>

#define HEADS 24
#define KVH   6
#define HD    64
#define BB    2
#define SS    2048
#define DD    1536
#define KVD   384      // KVH*HD
#define QKD   1920     // DD + KVD (Q|K only; V lives in VT)
#define MM    4096     // BB*SS

typedef unsigned short ushort_t;
typedef __attribute__((ext_vector_type(8))) short short8;
typedef __attribute__((ext_vector_type(4))) short short4v;
typedef __attribute__((ext_vector_type(4))) float f32x4;

__device__ __forceinline__ ushort_t f2bf(float f) {
    union { float f; unsigned u; } v; v.f = f;
    return (ushort_t)((v.u + 0x8000u) >> 16);
}
__device__ __forceinline__ unsigned pk2(float a, float b) {
    union { float f; unsigned u; } x, y; x.f = a; y.f = b;
    return ((x.u + 0x8000u) >> 16) | (((y.u + 0x8000u) >> 16) << 16);
}
// truncation pack (P values: common-mode cancels in softmax)
__device__ __forceinline__ unsigned pk2t(float a, float b) {
    union { float f; unsigned u; } x, y; x.f = a; y.f = b;
    return (x.u >> 16) | (y.u & 0xFFFF0000u);
}
// Schraudolph fast 2^s (±3.5% rel; cancels in p/Σp)
__device__ __forceinline__ float fexp2(float s) {
    float t = fmaf(s, 8388608.0f, 1065055420.0f);   // (127 - 0.0355) * 2^23
    union { int i; float f; } v; v.i = (int)t;
    return v.f;
}
// 16B frag read from an 8B-aligned LDS row: two b64 halves.
__device__ __forceinline__ short8 lds_frag8(const ushort_t* p) {
    short4v lo = *(const short4v*)p;
    short4v hi = *(const short4v*)(p + 4);
    return __builtin_shufflevector(lo, hi, 0, 1, 2, 3, 4, 5, 6, 7);
}
// async global->LDS, 16B per lane; lds ptr must be wave-uniform base.
__device__ __forceinline__ void glds16(const void* g, void* l) {
    __builtin_amdgcn_global_load_lds(
        (const __attribute__((address_space(1))) void*)g,
        (__attribute__((address_space(3))) void*)l, 16, 0, 0);
}

// ---------------------------------------------------------------------------
// K0: fused preprocessing — cvt X + 4x weight transpose-convert.
// ---------------------------------------------------------------------------
__device__ __forceinline__ void tconv_body(const float* __restrict__ in,
                                           ushort_t* __restrict__ out,
                                           int R, int C, int cb, int rb)
{
    __shared__ ushort_t tile[32][33];
    const int tx = threadIdx.x & 31, ty = threadIdx.x >> 5;
    const int c0 = cb * 32, r0 = rb * 32;
#pragma unroll
    for (int i = 0; i < 4; ++i)
        tile[ty + i * 8][tx] = f2bf(in[(size_t)(r0 + ty + i * 8) * C + c0 + tx]);
    __syncthreads();
#pragma unroll
    for (int i = 0; i < 4; ++i)
        out[(size_t)(c0 + ty + i * 8) * R + r0 + tx] = tile[tx][ty + i * 8];
}

#define NCVT (MM * DD / 4 / 256)     // 6144
__global__ __launch_bounds__(256) void k_prep(const float* __restrict__ HS,
                                              const float* __restrict__ Wq,
                                              const float* __restrict__ Wk,
                                              const float* __restrict__ Wv,
                                              const float* __restrict__ Wo,
                                              ushort_t* __restrict__ Xbf,
                                              ushort_t* __restrict__ Wqt,
                                              ushort_t* __restrict__ Wkt,
                                              ushort_t* __restrict__ Wvt,
                                              ushort_t* __restrict__ Wot)
{
    int bid = blockIdx.x;
    if (bid < NCVT) {
        int i = bid * 256 + threadIdx.x;
        float4 v = ((const float4*)HS)[i];
        uint2 o = { pk2(v.x, v.y), pk2(v.z, v.w) };
        ((uint2*)Xbf)[i] = o;
        return;
    }
    bid -= NCVT;
    if (bid < 2304) { tconv_body(Wq, Wqt, DD, DD,  bid % 48, bid / 48); return; }
    bid -= 2304;
    if (bid < 576)  { tconv_body(Wk, Wkt, DD, KVD, bid % 12, bid / 12); return; }
    bid -= 576;
    if (bid < 576)  { tconv_body(Wv, Wvt, DD, KVD, bid % 12, bid / 12); return; }
    bid -= 576;
    tconv_body(Wo, Wot, DD, DD, bid % 48, bid / 48);
}

// ---------------------------------------------------------------------------
// K1: fused projection dispatch (R4/R7 structure — the best-measured 248.1us
// config; R10's BK=64 reverted, null result).
//   bid <  480 : Q|K projection, 128x128 tiles + RoPE + Q-scale
//   bid >= 480 : V^T GEMM -> VT, k-PERMUTED slot map
//                s = 32*kc + 8*quad + 2*r + j4 <-> tok = 32*kc+16*j4+4*quad+r
// ---------------------------------------------------------------------------
__global__ __launch_bounds__(256) void k_proj(const ushort_t* __restrict__ Xbf,
                                              const ushort_t* __restrict__ Wqt,
                                              const ushort_t* __restrict__ Wkt,
                                              const ushort_t* __restrict__ Wvt,
                                              const float* __restrict__ cosb,
                                              const float* __restrict__ sinb,
                                              ushort_t* __restrict__ QKVb,
                                              ushort_t* __restrict__ VT)
{
    __shared__ ushort_t As[128][32];
    __shared__ ushort_t Bs[128][32];
    const int t = threadIdx.x, lane = t & 63, wave = t >> 6;
    const int n16 = lane & 15, quad = lane >> 4;
    const int wr = wave >> 1, wc = wave & 1;
    const int srow = lane >> 2;
    const int scol = (lane & 3) * 8;

    if (blockIdx.x < 480) {
        // ---------------- Q|K projection ----------------
        const int nt = blockIdx.x % 15;
        const int n0 = nt * 128;
        const int m0 = (blockIdx.x / 15) * 128;
        const ushort_t* Bt; int nl, isq;
        if (nt < 12) { Bt = Wqt; nl = n0;      isq = 1; }
        else         { Bt = Wkt; nl = n0 - DD; isq = 0; }

        const size_t aoff0 = (size_t)(m0 + wave * 16 + srow) * DD + scol;
        const size_t aoff1 = (size_t)(m0 + (wave + 4) * 16 + srow) * DD + scol;
        const size_t boff0 = (size_t)(nl + wave * 16 + srow) * DD + scol;
        const size_t boff1 = (size_t)(nl + (wave + 4) * 16 + srow) * DD + scol;
        ushort_t* lA0 = &As[wave * 16][0];
        ushort_t* lA1 = &As[(wave + 4) * 16][0];
        ushort_t* lB0 = &Bs[wave * 16][0];
        ushort_t* lB1 = &Bs[(wave + 4) * 16][0];

        f32x4 acc[4][4] = {};
        for (int k0 = 0; k0 < DD; k0 += 32) {
            __syncthreads();
            glds16(Xbf + aoff0 + k0, lA0);
            glds16(Xbf + aoff1 + k0, lA1);
            glds16(Bt  + boff0 + k0, lB0);
            glds16(Bt  + boff1 + k0, lB1);
            __syncthreads();
            short8 af[4], bf8[4];
#pragma unroll
            for (int i = 0; i < 4; ++i) af[i]  = *(const short8*)&As[wr * 64 + i * 16 + n16][quad * 8];
#pragma unroll
            for (int j = 0; j < 4; ++j) bf8[j] = *(const short8*)&Bs[wc * 64 + j * 16 + n16][quad * 8];
#pragma unroll
            for (int i = 0; i < 4; ++i)
#pragma unroll
                for (int j = 0; j < 4; ++j)
                    acc[i][j] = __builtin_amdgcn_mfma_f32_16x16x32_bf16(af[i], bf8[j], acc[i][j], 0, 0, 0);
        }

        const float QSC = 0.18033688011112042f;   // 0.125 * log2(e)
#pragma unroll
        for (int i = 0; i < 4; ++i) {
#pragma unroll
            for (int r = 0; r < 4; ++r) {
                const int row = m0 + wr * 64 + i * 16 + quad * 4 + r;
                ushort_t* outp = QKVb + (size_t)row * QKD + n0 + wc * 64 + n16;
                float v0 = acc[i][0][r], v1 = acc[i][1][r];
                float v2 = acc[i][2][r], v3 = acc[i][3][r];
                {   // partial RoPE on head dims 0..31 (Q and K)
                    const int s = row & (SS - 1);
                    float c0 = cosb[s * 32 + n16],      s0 = sinb[s * 32 + n16];
                    float c1 = cosb[s * 32 + 16 + n16], s1 = sinb[s * 32 + 16 + n16];
                    float nr = v0 * c0 - v1 * s0;
                    float ni = v1 * c1 + v0 * s1;
                    v0 = nr; v1 = ni;
                }
                if (isq) { v0 *= QSC; v1 *= QSC; v2 *= QSC; v3 *= QSC; }
                outp[0]  = f2bf(v0);
                outp[16] = f2bf(v1);
                outp[32] = f2bf(v2);
                outp[48] = f2bf(v3);
            }
        }
    } else {
        // ---------------- V^T GEMM (k-permuted epilogue) ----------------
        const int vb = blockIdx.x - 480;
        const int n0 = (vb & 31) * 128;    // tokens
        const int m0 = (vb >> 5) * 64;     // channels c

        const size_t aoff  = (size_t)(m0 + wave * 16 + srow) * DD + scol;
        const size_t boff0 = (size_t)(n0 + wave * 32 + srow) * DD + scol;
        const size_t boff1 = boff0 + (size_t)16 * DD;
        ushort_t* lA  = &As[wave * 16][0];
        ushort_t* lB0 = &Bs[wave * 32][0];
        ushort_t* lB1 = &Bs[wave * 32 + 16][0];

        f32x4 acc[2][4] = {};
        for (int k0 = 0; k0 < DD; k0 += 32) {
            __syncthreads();
            glds16(Wvt + aoff  + k0, lA);
            glds16(Xbf + boff0 + k0, lB0);
            glds16(Xbf + boff1 + k0, lB1);
            __syncthreads();
            short8 af[2], bf8[4];
#pragma unroll
            for (int i = 0; i < 2; ++i) af[i]  = *(const short8*)&As[wr * 32 + i * 16 + n16][quad * 8];
#pragma unroll
            for (int j = 0; j < 4; ++j) bf8[j] = *(const short8*)&Bs[wc * 64 + j * 16 + n16][quad * 8];
#pragma unroll
            for (int i = 0; i < 2; ++i)
#pragma unroll
                for (int j = 0; j < 4; ++j)
                    acc[i][j] = __builtin_amdgcn_mfma_f32_16x16x32_bf16(af[i], bf8[j], acc[i][j], 0, 0, 0);
        }

        const int b = n0 >> 11;            // token tile never straddles batch
        const int s0 = 8 * (n16 >> 2) + 2 * (n16 & 3);
#pragma unroll
        for (int i = 0; i < 2; ++i)
#pragma unroll
            for (int r = 0; r < 4; ++r) {
                const int c = m0 + wr * 32 + i * 16 + quad * 4 + r;
                ushort_t* op = VT + ((size_t)b * KVD + c) * SS +
                               (n0 & (SS - 1)) + wc * 64 + s0;
                *(unsigned*)op        = pk2(acc[i][0][r], acc[i][1][r]);
                *(unsigned*)(op + 32) = pk2(acc[i][2][r], acc[i][3][r]);
            }
    }
}

// ---------------------------------------------------------------------------
// K3: MFMA bf16 flash attention — R7 structure VERBATIM (best measured:
// 75.6us, occupancy 49%, 0 bank conflicts).  512 threads / 8 waves x 16q,
// swapped QK^T, in-register P, fast-exp2, double-buffered Ks/Vs, one
// barrier/tile, prefetch-1 reg staging.
// ---------------------------------------------------------------------------
__global__ __launch_bounds__(512, 6) void k_attn(const ushort_t* __restrict__ QKVb,
                                                 const ushort_t* __restrict__ VT,
                                                 ushort_t* __restrict__ AOb)
{
    __shared__ __align__(16) ushort_t Ks[2][64][76];
    __shared__ __align__(16) ushort_t Vs[2][64][76];   // Vs[buf][d][slot]

    const int t    = threadIdx.x;
    const int wave = t >> 6;          // 0..7 -> q-range wave*16
    const int quad = (t >> 4) & 3;
    const int n16  = t & 15;
    const int q0   = blockIdx.x * 128;
    const int h    = blockIdx.y;
    const int b    = blockIdx.z;
    const int kh   = h >> 2;

    const int sr = t >> 3;            // 0..63 staging row (8 lanes/row)
    const int sc = (t & 7) * 8;       // ushort col: 8 lanes x 16B = 128B row

    // loop-invariant Q frags from global (pre-scaled by 0.125*log2e)
    short8 qf[2];
#pragma unroll
    for (int kc = 0; kc < 2; ++kc)
        qf[kc] = *(const short8*)(QKVb +
            (size_t)(b * SS + q0 + wave * 16 + n16) * QKD +
            h * HD + kc * 32 + quad * 8);

    float l_p = 0.0f;                 // per-lane partial row sum (q = n16)
    f32x4 acc_o[4] = {};              // C[d][q]: row d = quad*4+r, col q = n16

    const ushort_t* Kbase = QKVb + (size_t)(b * SS) * QKD + DD + kh * HD;
    const ushort_t* Vbase = VT + ((size_t)b * KVD + kh * 64) * SS;

    uint4 kv, vv;                     // prefetch registers (one tile)

#define LOAD_TILE(K0) do {                                                  \
        kv = *(const uint4*)(Kbase + (size_t)((K0) + sr) * QKD + sc);       \
        vv = *(const uint4*)(Vbase + (size_t)sr * SS + (K0) + sc);          \
    } while (0)

#define WRITE_BUF(BI) do {                                                  \
        *(uint2*)&Ks[BI][sr][sc]     = make_uint2(kv.x, kv.y);              \
        *(uint2*)&Ks[BI][sr][sc + 4] = make_uint2(kv.z, kv.w);              \
        *(uint2*)&Vs[BI][sr][sc]     = make_uint2(vv.x, vv.y);              \
        *(uint2*)&Vs[BI][sr][sc + 4] = make_uint2(vv.z, vv.w);              \
    } while (0)

    // ---- prologue: tile 0 -> buf0; issue tile 1; barrier ----
    LOAD_TILE(0);
    WRITE_BUF(0);
    LOAD_TILE(64);
    __syncthreads();

    const int NT = SS / 64;
    for (int kt = 0; kt < NT; ++kt) {
        const int cur = kt & 1;
        const ushort_t (*Kc)[76] = Ks[cur];
        const ushort_t (*Vc)[76] = Vs[cur];

        // ---- swapped QK^T: S^T[64k][16q] per wave ----
        f32x4 sT[4] = {};
#pragma unroll
        for (int kc = 0; kc < 2; ++kc) {
            short8 bf[4];
#pragma unroll
            for (int jj = 0; jj < 4; ++jj)
                bf[jj] = lds_frag8(&Kc[jj * 16 + n16][kc * 32 + quad * 8]);
#pragma unroll
            for (int jj = 0; jj < 4; ++jj)
                sT[jj] = __builtin_amdgcn_mfma_f32_16x16x32_bf16(
                    bf[jj], qf[kc], sT[jj], 0, 0, 0);
        }

        // ---- softmax fully in-register: pb[kc] = PV B-frag words ----
        union PB { unsigned w[4]; short8 v; };
        PB pb[2];
#pragma unroll
        for (int w = 0; w < 4; ++w) {
            float p0 = fexp2(sT[0][w]);
            float p1 = fexp2(sT[1][w]);
            float p2 = fexp2(sT[2][w]);
            float p3 = fexp2(sT[3][w]);
            pb[0].w[w] = pk2t(p0, p1);   // slots j=2w,2w+1 of kc=0
            pb[1].w[w] = pk2t(p2, p3);   // slots j=2w,2w+1 of kc=1
            l_p += (p0 + p1) + (p2 + p3);
        }

        // ---- PV: acc_o[dd] += V^T-frag x P^T-frag ----
#pragma unroll
        for (int kc = 0; kc < 2; ++kc) {
            short8 vb[4];
#pragma unroll
            for (int dd = 0; dd < 4; ++dd)
                vb[dd] = lds_frag8(&Vc[dd * 16 + n16][kc * 32 + quad * 8]);
#pragma unroll
            for (int dd = 0; dd < 4; ++dd)
                acc_o[dd] = __builtin_amdgcn_mfma_f32_16x16x32_bf16(
                    vb[dd], pb[kc].v, acc_o[dd], 0, 0, 0);
        }

        // ---- stage next tile into the other buffer; issue tile kt+2 ----
        if (kt + 1 < NT) {
            WRITE_BUF(cur ^ 1);            // vmcnt wait lands here (hidden)
            if (kt + 2 < NT)
                LOAD_TILE((kt + 2) * 64);
            __syncthreads();
        }
    }
#undef LOAD_TILE
#undef WRITE_BUF

    // ---- epilogue: reduce l across quads (same q = n16), packed O stores --
    {
        float s = l_p;
        s += __shfl_xor(s, 16);
        s += __shfl_xor(s, 32);
        const float inv = 1.0f / s;
        const int q = q0 + wave * 16 + n16;
        ushort_t* op = AOb + (size_t)(b * SS + q) * DD + h * HD + quad * 4;
#pragma unroll
        for (int dd = 0; dd < 4; ++dd) {
            uint2 o = { pk2(acc_o[dd][0] * inv, acc_o[dd][1] * inv),
                        pk2(acc_o[dd][2] * inv, acc_o[dd][3] * inv) };
            *(uint2*)(op + dd * 16) = o;
        }
    }
}

// ---------------------------------------------------------------------------
// K4: MFMA out-proj.  out[MM][DD](fp32) = AOb @ Wot^T + bo + HS.
// ROUND 11 change: 64x128 -> 128x128 tile (acc 4x4 per wave — same density
// as the QK branch; was acc 2x4 = half the MFMA per staged byte/barrier).
// Grid (12, 32) = 384 blocks (~1.5/CU, ~25% tail imbalance; net model
// ~1.7x density x 0.75 utilization ≈ 1.3x).  BK=32 R4 staging structure.
// ---------------------------------------------------------------------------
__global__ __launch_bounds__(256) void k_out_mfma(const ushort_t* __restrict__ AOb,
                                                  const ushort_t* __restrict__ Wot,
                                                  const float* __restrict__ bo,
                                                  const float* __restrict__ HS,
                                                  float* __restrict__ out)
{
    __shared__ ushort_t As[128][32];   // AOb rows (m)
    __shared__ ushort_t Bs[128][32];   // Wot rows (n)
    const int t = threadIdx.x, lane = t & 63, wave = t >> 6;
    const int n16 = lane & 15, quad = lane >> 4;
    const int wr = wave >> 1, wc = wave & 1;
    const int n0 = blockIdx.x * 128;
    const int m0 = blockIdx.y * 128;

    const int srow = lane >> 2;
    const int scol = (lane & 3) * 8;
    const size_t aoff0 = (size_t)(m0 + wave * 16 + srow) * DD + scol;
    const size_t aoff1 = (size_t)(m0 + (wave + 4) * 16 + srow) * DD + scol;
    const size_t boff0 = (size_t)(n0 + wave * 16 + srow) * DD + scol;
    const size_t boff1 = (size_t)(n0 + (wave + 4) * 16 + srow) * DD + scol;
    ushort_t* lA0 = &As[wave * 16][0];
    ushort_t* lA1 = &As[(wave + 4) * 16][0];
    ushort_t* lB0 = &Bs[wave * 16][0];
    ushort_t* lB1 = &Bs[(wave + 4) * 16][0];

    f32x4 acc[4][4] = {};
    for (int k0 = 0; k0 < DD; k0 += 32) {
        __syncthreads();
        glds16(AOb + aoff0 + k0, lA0);
        glds16(AOb + aoff1 + k0, lA1);
        glds16(Wot + boff0 + k0, lB0);
        glds16(Wot + boff1 + k0, lB1);
        __syncthreads();
        short8 af[4], bf8[4];
#pragma unroll
        for (int i = 0; i < 4; ++i) af[i]  = *(const short8*)&As[wr * 64 + i * 16 + n16][quad * 8];
#pragma unroll
        for (int j = 0; j < 4; ++j) bf8[j] = *(const short8*)&Bs[wc * 64 + j * 16 + n16][quad * 8];
#pragma unroll
        for (int i = 0; i < 4; ++i)
#pragma unroll
            for (int j = 0; j < 4; ++j)
                acc[i][j] = __builtin_amdgcn_mfma_f32_16x16x32_bf16(af[i], bf8[j], acc[i][j], 0, 0, 0);
    }

    const int colb = n0 + wc * 64 + n16;
    float bo4[4];
#pragma unroll
    for (int j = 0; j < 4; ++j) bo4[j] = bo[colb + j * 16];
#pragma unroll
    for (int i = 0; i < 4; ++i) {
#pragma unroll
        for (int r = 0; r < 4; ++r) {
            const int row = m0 + wr * 64 + i * 16 + quad * 4 + r;
            float* op = out + (size_t)row * DD + colb;
            const float* hp = HS + (size_t)row * DD + colb;
#pragma unroll
            for (int j = 0; j < 4; ++j)
                op[j * 16] = acc[i][j][r] + bo4[j] + hp[j * 16];
        }
    }
}

extern "C" void kernel_launch(void* const* d_in, const int* in_sizes, int n_in,
                              void* d_out, int out_size, void* d_ws, size_t ws_size,
                              hipStream_t stream)
{
    const float* HS   = (const float*)d_in[0];
    const float* cosb = (const float*)d_in[1];
    const float* sinb = (const float*)d_in[2];
    const float* Wq   = (const float*)d_in[3];
    const float* Wk   = (const float*)d_in[4];
    const float* Wv   = (const float*)d_in[5];
    const float* Wo   = (const float*)d_in[6];
    const float* bo   = (const float*)d_in[7];
    float* out = (float*)d_out;

    ushort_t* Xbf  = (ushort_t*)d_ws;                  // [MM][DD]
    ushort_t* QKVb = Xbf  + (size_t)MM * DD;           // [MM][QKD]
    ushort_t* AOb  = QKVb + (size_t)MM * QKD;          // [MM][DD]
    ushort_t* Wqt  = AOb  + (size_t)MM * DD;           // [DD][DD]
    ushort_t* Wkt  = Wqt  + (size_t)DD * DD;           // [KVD][DD]
    ushort_t* Wvt  = Wkt  + (size_t)KVD * DD;          // [KVD][DD]
    ushort_t* Wot  = Wvt  + (size_t)KVD * DD;          // [DD][DD]
    ushort_t* VT   = Wot  + (size_t)DD * DD;           // [BB][KVD][SS] (k-permuted)

    const int nprep = NCVT + 2304 + 576 + 576 + 2304;
    k_prep    <<<dim3(nprep), 256, 0, stream>>>(HS, Wq, Wk, Wv, Wo,
                                                Xbf, Wqt, Wkt, Wvt, Wot);
    k_proj    <<<dim3(480 + 192), 256, 0, stream>>>(Xbf, Wqt, Wkt, Wvt,
                                                    cosb, sinb, QKVb, VT);
    k_attn    <<<dim3(SS / 128, HEADS, BB), 512, 0, stream>>>(QKVb, VT, AOb);
    k_out_mfma<<<dim3(DD / 128, MM / 128), 256, 0, stream>>>(AOb, Wot, bo, HS, out);
}